// Round 9
// baseline (145.027 us; speedup 1.0000x reference)
//
#include <hip/hip_runtime.h>
#include <hip/hip_cooperative_groups.h>

namespace cg = cooperative_groups;

#define IN_FEATS 128
#define HIDDEN 32

typedef short v8s __attribute__((ext_vector_type(8)));
typedef unsigned short u16x8 __attribute__((ext_vector_type(8)));
typedef float v4f __attribute__((ext_vector_type(4)));

__device__ __forceinline__ unsigned short f2bf(float x) {
    union { float f; unsigned int u; } v; v.f = x;
    const unsigned int r = v.u + 0x7fffu + ((v.u >> 16) & 1u);   // RNE
    return (unsigned short)(r >> 16);
}
__device__ __forceinline__ float bf2f(unsigned short b) {
    union { float f; unsigned int u; } v; v.u = ((unsigned int)b) << 16;
    return v.f;
}

// ---------------------------------------------------------------------------
// Fused cooperative kernel: pack (per-block LDS) -> precompute P -> grid.sync
// -> edge classify. One launch, one grid-wide barrier.
//
// Fragment slot g = (nb*4 + ks)*64 + lane holds B[k][u], u = nb*16+(lane&15),
// k = ks*32 + ((lane>>4)&3)*8 + j (j=0..7). A uses the identical map, so any
// common k-permutation cancels in the MFMA K-sum.
// C/D (HW-verified): col = lane&15, row = (lane>>4)*4 + reg.
// ---------------------------------------------------------------------------
__global__ __launch_bounds__(256, 4) void fused_edge_classifier(
    const float* __restrict__ embed,
    const float* __restrict__ W1,
    const float* __restrict__ b1,
    const float* __restrict__ W2,
    const float* __restrict__ b2,
    const int* __restrict__ src,
    const int* __restrict__ dst,
    unsigned short* __restrict__ P,        // bf16 [n][64] workspace
    float* __restrict__ out,
    int n_nodes,
    int n_edges)
{
    __shared__ unsigned short sBhi[8192];  // 16 KB
    __shared__ unsigned short sBlo[8192];  // 16 KB

    const int t    = threadIdx.x;
    const int lane = t & 63;
    const int wave = t >> 6;

    // ---- Phase 0: per-block W fragment pack into LDS (no grid sync) ----
#pragma unroll
    for (int g0 = 0; g0 < 1024; g0 += 256) {
        const int g   = g0 + t;                 // (nb*4+ks)*64 + lane
        const int gl  = g & 63;
        const int ks  = (g >> 6) & 3;
        const int nb  = g >> 8;
        const int u   = nb * 16 + (gl & 15);
        const int k0  = ks * 32 + ((gl >> 4) & 3) * 8;
        const float* wp = W1 + (u & 31) * (2 * IN_FEATS) + (u >> 5) * IN_FEATS + k0;
        const float4 x0 = *reinterpret_cast<const float4*>(wp);
        const float4 x1 = *reinterpret_cast<const float4*>(wp + 4);
        const float xs[8] = {x0.x, x0.y, x0.z, x0.w, x1.x, x1.y, x1.z, x1.w};
        v8s h, l;
#pragma unroll
        for (int j = 0; j < 8; ++j) {
            const unsigned short hb = f2bf(xs[j]);
            h[j] = (short)hb;
            l[j] = (short)f2bf(xs[j] - bf2f(hb));
        }
        *reinterpret_cast<v8s*>(sBhi + g * 8) = h;
        *reinterpret_cast<v8s*>(sBlo + g * 8) = l;
    }
    __syncthreads();

    // ---- Phase 1: P[n][0:64] = embed[n] @ [W1s|W1d].T  (split-bf16 MFMA) ----
    const int last = n_nodes - 1;
    const int grp  = lane >> 4;
    const int gwid = blockIdx.x * 4 + wave;
    const int nw   = gridDim.x * 4;
    const int ntiles = (n_nodes + 15) >> 4;

    for (int tile = gwid; tile < ntiles; tile += nw) {
        const int node0 = tile << 4;
        const int row   = min(node0 + (lane & 15), last);

        v8s ahi[4], alo[4];
#pragma unroll
        for (int ks = 0; ks < 4; ++ks) {
            const float* ap = embed + (size_t)row * IN_FEATS + ks * 32 + grp * 8;
            const float4 x0 = *reinterpret_cast<const float4*>(ap);
            const float4 x1 = *reinterpret_cast<const float4*>(ap + 4);
            const float xs[8] = {x0.x, x0.y, x0.z, x0.w, x1.x, x1.y, x1.z, x1.w};
            v8s h, l;
#pragma unroll
            for (int j = 0; j < 8; ++j) {
                const unsigned short hb = f2bf(xs[j]);
                h[j] = (short)hb;
                l[j] = (short)f2bf(xs[j] - bf2f(hb));
            }
            ahi[ks] = h;
            alo[ks] = l;
        }

#pragma unroll
        for (int nb = 0; nb < 4; ++nb) {
            v8s bhi[4], blo[4];
#pragma unroll
            for (int ks = 0; ks < 4; ++ks) {
                const int fi = ((nb * 4 + ks) * 64 + lane) * 8;
                bhi[ks] = *reinterpret_cast<const v8s*>(sBhi + fi);
                blo[ks] = *reinterpret_cast<const v8s*>(sBlo + fi);
            }
            v4f acc = {0.f, 0.f, 0.f, 0.f};
#pragma unroll
            for (int ks = 0; ks < 4; ++ks) {
                acc = __builtin_amdgcn_mfma_f32_16x16x32_bf16(ahi[ks], bhi[ks], acc, 0, 0, 0);
                acc = __builtin_amdgcn_mfma_f32_16x16x32_bf16(ahi[ks], blo[ks], acc, 0, 0, 0);
                acc = __builtin_amdgcn_mfma_f32_16x16x32_bf16(alo[ks], bhi[ks], acc, 0, 0, 0);
            }
            const int u = nb * 16 + (lane & 15);
#pragma unroll
            for (int r = 0; r < 4; ++r) {
                const int n = node0 + grp * 4 + r;
                if (n < n_nodes)
                    P[(size_t)n * 64 + u] = f2bf(acc[r]);
            }
        }
    }

    // ---- grid-wide barrier: P visible device-wide ----
    cg::this_grid().sync();

    // ---- Phase 2: edges, 4 lanes/edge, grid-stride with 2x unroll ----
    const int q = t & 3;
    const float4 b1a = *reinterpret_cast<const float4*>(b1 + q * 8);
    const float4 b1b = *reinterpret_cast<const float4*>(b1 + q * 8 + 4);
    const float4 w0a = *reinterpret_cast<const float4*>(W2 + q * 8);
    const float4 w0b = *reinterpret_cast<const float4*>(W2 + q * 8 + 4);
    const float4 w1a = *reinterpret_cast<const float4*>(W2 + HIDDEN + q * 8);
    const float4 w1b = *reinterpret_cast<const float4*>(W2 + HIDDEN + q * 8 + 4);
    const float bb1[8] = {b1a.x, b1a.y, b1a.z, b1a.w, b1b.x, b1b.y, b1b.z, b1b.w};
    const float ww0[8] = {w0a.x, w0a.y, w0a.z, w0a.w, w0b.x, w0b.y, w0b.z, w0b.w};
    const float ww1[8] = {w1a.x, w1a.y, w1a.z, w1a.w, w1b.x, w1b.y, w1b.z, w1b.w};
    const float bias0 = b2[0], bias1 = b2[1];

    const int qid0 = (blockIdx.x * 256 + t) >> 2;
    const int nq   = gridDim.x * 64;

    for (int e = qid0; e < n_edges; e += 2 * nq) {
        const int eBr = e + nq;
        const bool hasB = eBr < n_edges;
        const int eB = hasB ? eBr : e;

        const int s1 = src[e],  d1 = dst[e];
        const int s2 = src[eB], d2 = dst[eB];
        const u16x8 ps1 = *reinterpret_cast<const u16x8*>(P + (size_t)s1 * 64 + q * 8);
        const u16x8 pd1 = *reinterpret_cast<const u16x8*>(P + (size_t)d1 * 64 + 32 + q * 8);
        const u16x8 ps2 = *reinterpret_cast<const u16x8*>(P + (size_t)s2 * 64 + q * 8);
        const u16x8 pd2 = *reinterpret_cast<const u16x8*>(P + (size_t)d2 * 64 + 32 + q * 8);

        float a0 = 0.f, a1 = 0.f, c0 = 0.f, c1 = 0.f;
#pragma unroll
        for (int j = 0; j < 8; ++j) {
            float h1 = bf2f(ps1[j]) + bf2f(pd1[j]) + bb1[j];
            float h2 = bf2f(ps2[j]) + bf2f(pd2[j]) + bb1[j];
            h1 = fmaxf(h1, 0.f);
            h2 = fmaxf(h2, 0.f);
            a0 = fmaf(h1, ww0[j], a0);
            a1 = fmaf(h1, ww1[j], a1);
            c0 = fmaf(h2, ww0[j], c0);
            c1 = fmaf(h2, ww1[j], c1);
        }
        a0 += __shfl_xor(a0, 1); a0 += __shfl_xor(a0, 2);
        a1 += __shfl_xor(a1, 1); a1 += __shfl_xor(a1, 2);
        c0 += __shfl_xor(c0, 1); c0 += __shfl_xor(c0, 2);
        c1 += __shfl_xor(c1, 1); c1 += __shfl_xor(c1, 2);
        if (q == 0) {
            *reinterpret_cast<float2*>(out + (size_t)e * 2) =
                make_float2(a0 + bias0, a1 + bias1);
            if (hasB)
                *reinterpret_cast<float2*>(out + (size_t)eBr * 2) =
                    make_float2(c0 + bias0, c1 + bias1);
        }
    }
}

// ===========================================================================
// Fallback path: the proven R8 three-kernel pipeline.
// ===========================================================================
__global__ __launch_bounds__(256) void pack_W_frags(
    const float* __restrict__ W1,
    unsigned short* __restrict__ Bhi,
    unsigned short* __restrict__ Blo)
{
    const int i = blockIdx.x * 256 + threadIdx.x;
    if (i >= 4 * 4 * 64 * 8) return;
    const int j    = i & 7;
    const int lane = (i >> 3) & 63;
    const int ks   = (i >> 9) & 3;
    const int nb   = i >> 11;
    const int u = nb * 16 + (lane & 15);
    const int k = ks * 32 + ((lane >> 4) & 3) * 8 + j;
    const float w = W1[(u & 31) * (2 * IN_FEATS) + (u >> 5) * IN_FEATS + k];
    const unsigned short hi = f2bf(w);
    Bhi[i] = hi;
    Blo[i] = f2bf(w - bf2f(hi));
}

__global__ __launch_bounds__(256, 4) void precompute_P_mfma(
    const float* __restrict__ embed,
    const unsigned short* __restrict__ Bhi,
    const unsigned short* __restrict__ Blo,
    unsigned short* __restrict__ P,
    int n_nodes)
{
    const int t    = threadIdx.x;
    const int lane = t & 63;
    const int wave = t >> 6;
    const int node0 = blockIdx.x * 64 + wave * 16;
    if (node0 >= n_nodes) return;
    const int last = n_nodes - 1;
    const int row  = min(node0 + (lane & 15), last);
    const int grp  = lane >> 4;

    v8s ahi[4], alo[4];
#pragma unroll
    for (int ks = 0; ks < 4; ++ks) {
        const float* ap = embed + (size_t)row * IN_FEATS + ks * 32 + grp * 8;
        const float4 x0 = *reinterpret_cast<const float4*>(ap);
        const float4 x1 = *reinterpret_cast<const float4*>(ap + 4);
        const float xs[8] = {x0.x, x0.y, x0.z, x0.w, x1.x, x1.y, x1.z, x1.w};
        v8s h, l;
#pragma unroll
        for (int j = 0; j < 8; ++j) {
            const unsigned short hb = f2bf(xs[j]);
            h[j] = (short)hb;
            l[j] = (short)f2bf(xs[j] - bf2f(hb));
        }
        ahi[ks] = h;
        alo[ks] = l;
    }

#pragma unroll
    for (int nb = 0; nb < 4; ++nb) {
        v8s bhi[4], blo[4];
#pragma unroll
        for (int ks = 0; ks < 4; ++ks) {
            const int fi = ((nb * 4 + ks) * 64 + lane) * 8;
            bhi[ks] = *reinterpret_cast<const v8s*>(Bhi + fi);
            blo[ks] = *reinterpret_cast<const v8s*>(Blo + fi);
        }
        v4f acc = {0.f, 0.f, 0.f, 0.f};
#pragma unroll
        for (int ks = 0; ks < 4; ++ks) {
            acc = __builtin_amdgcn_mfma_f32_16x16x32_bf16(ahi[ks], bhi[ks], acc, 0, 0, 0);
            acc = __builtin_amdgcn_mfma_f32_16x16x32_bf16(ahi[ks], blo[ks], acc, 0, 0, 0);
            acc = __builtin_amdgcn_mfma_f32_16x16x32_bf16(alo[ks], bhi[ks], acc, 0, 0, 0);
        }
        const int u = nb * 16 + (lane & 15);
#pragma unroll
        for (int r = 0; r < 4; ++r) {
            const int n = node0 + grp * 4 + r;
            if (n < n_nodes)
                P[(size_t)n * 64 + u] = f2bf(acc[r]);
        }
    }
}

__global__ __launch_bounds__(256) void edge_classify_bf16(
    const int* __restrict__ src,
    const int* __restrict__ dst,
    const unsigned short* __restrict__ P,
    const float* __restrict__ b1,
    const float* __restrict__ W2,
    const float* __restrict__ b2,
    float* __restrict__ out,
    int n_edges)
{
    const int t = threadIdx.x;
    const int e = blockIdx.x * 64 + (t >> 2);
    if (e >= n_edges) return;
    const int q = t & 3;
    const int s = src[e];
    const int d = dst[e];

    const u16x8 ps = *reinterpret_cast<const u16x8*>(P + (size_t)s * 64 + q * 8);
    const u16x8 pd = *reinterpret_cast<const u16x8*>(P + (size_t)d * 64 + 32 + q * 8);

    const float4 b1a = *reinterpret_cast<const float4*>(b1 + q * 8);
    const float4 b1b = *reinterpret_cast<const float4*>(b1 + q * 8 + 4);
    const float4 w0a = *reinterpret_cast<const float4*>(W2 + q * 8);
    const float4 w0b = *reinterpret_cast<const float4*>(W2 + q * 8 + 4);
    const float4 w1a = *reinterpret_cast<const float4*>(W2 + HIDDEN + q * 8);
    const float4 w1b = *reinterpret_cast<const float4*>(W2 + HIDDEN + q * 8 + 4);
    const float bb1[8] = {b1a.x, b1a.y, b1a.z, b1a.w, b1b.x, b1b.y, b1b.z, b1b.w};
    const float ww0[8] = {w0a.x, w0a.y, w0a.z, w0a.w, w0b.x, w0b.y, w0b.z, w0b.w};
    const float ww1[8] = {w1a.x, w1a.y, w1a.z, w1a.w, w1b.x, w1b.y, w1b.z, w1b.w};

    float l0 = 0.f, l1 = 0.f;
#pragma unroll
    for (int j = 0; j < 8; ++j) {
        float h = bf2f(ps[j]) + bf2f(pd[j]) + bb1[j];
        h = fmaxf(h, 0.f);
        l0 = fmaf(h, ww0[j], l0);
        l1 = fmaf(h, ww1[j], l1);
    }
    l0 += __shfl_xor(l0, 1); l0 += __shfl_xor(l0, 2);
    l1 += __shfl_xor(l1, 1); l1 += __shfl_xor(l1, 2);
    if (q == 0)
        *reinterpret_cast<float2*>(out + (size_t)e * 2) =
            make_float2(l0 + b2[0], l1 + b2[1]);
}

__global__ __launch_bounds__(256) void edge_direct(
    const int* __restrict__ src, const int* __restrict__ dst,
    const float* __restrict__ embed,
    const float* __restrict__ W1, const float* __restrict__ b1,
    const float* __restrict__ W2, const float* __restrict__ b2,
    float* __restrict__ out, int n_edges)
{
    const int e = blockIdx.x * 256 + threadIdx.x;
    if (e >= n_edges) return;
    const int s = src[e], d = dst[e];
    const float* se = embed + (size_t)s * IN_FEATS;
    const float* de = embed + (size_t)d * IN_FEATS;

    float acc[HIDDEN];
#pragma unroll
    for (int hh = 0; hh < HIDDEN; ++hh) acc[hh] = b1[hh];

    for (int c = 0; c < 4; ++c) {
        float es[32], ed[32];
#pragma unroll
        for (int q = 0; q < 8; ++q) {
            const float4 v = *reinterpret_cast<const float4*>(se + c * 32 + q * 4);
            es[q*4+0] = v.x; es[q*4+1] = v.y; es[q*4+2] = v.z; es[q*4+3] = v.w;
            const float4 u = *reinterpret_cast<const float4*>(de + c * 32 + q * 4);
            ed[q*4+0] = u.x; ed[q*4+1] = u.y; ed[q*4+2] = u.z; ed[q*4+3] = u.w;
        }
#pragma unroll
        for (int hh = 0; hh < HIDDEN; ++hh) {
            float acch = acc[hh];
#pragma unroll
            for (int k = 0; k < 32; ++k) {
                acch = fmaf(es[k], W1[hh * 256 + c * 32 + k], acch);
                acch = fmaf(ed[k], W1[hh * 256 + 128 + c * 32 + k], acch);
            }
            acc[hh] = acch;
        }
    }

    float l0 = b2[0], l1 = b2[1];
#pragma unroll
    for (int hh = 0; hh < HIDDEN; ++hh) {
        const float hv = fmaxf(acc[hh], 0.f);
        l0 = fmaf(hv, W2[hh], l0);
        l1 = fmaf(hv, W2[HIDDEN + hh], l1);
    }
    *reinterpret_cast<float2*>(out + (size_t)e * 2) = make_float2(l0, l1);
}

extern "C" void kernel_launch(void* const* d_in, const int* in_sizes, int n_in,
                              void* d_out, int out_size, void* d_ws, size_t ws_size,
                              hipStream_t stream)
{
    const int*   src = (const int*)d_in[0];
    const int*   dst = (const int*)d_in[1];
    const float* emb = (const float*)d_in[2];
    const float* W1  = (const float*)d_in[3];
    const float* b1  = (const float*)d_in[4];
    const float* W2  = (const float*)d_in[5];
    const float* b2  = (const float*)d_in[6];
    float* out = (float*)d_out;

    const int n_edges = in_sizes[0];
    const int n_nodes = in_sizes[2] / IN_FEATS;

    const size_t p_bytes = (size_t)n_nodes * 64 * sizeof(unsigned short);
    const size_t b_elems = 4 * 4 * 64 * 8;

    if (ws_size < p_bytes + 2 * b_elems * sizeof(unsigned short)) {
        const int nb_edges = (n_edges + 255) / 256;
        edge_direct<<<nb_edges, 256, 0, stream>>>(src, dst, emb, W1, b1, W2, b2, out, n_edges);
        return;
    }

    unsigned short* P = (unsigned short*)d_ws;

    // --- try single fused cooperative launch ---
    int dev = 0;
    (void)hipGetDevice(&dev);
    hipDeviceProp_t prop;
    int coop_ok = (hipGetDeviceProperties(&prop, dev) == hipSuccess) &&
                  prop.cooperativeLaunch;
    int blocks_per_cu = 0;
    if (coop_ok) {
        coop_ok = (hipOccupancyMaxActiveBlocksPerMultiprocessor(
                       &blocks_per_cu, (const void*)fused_edge_classifier,
                       256, 0) == hipSuccess) && blocks_per_cu > 0;
    }
    if (coop_ok) {
        const int grid = blocks_per_cu * prop.multiProcessorCount;
        void* args[] = {
            (void*)&emb, (void*)&W1, (void*)&b1, (void*)&W2, (void*)&b2,
            (void*)&src, (void*)&dst, (void*)&P, (void*)&out,
            (void*)&n_nodes, (void*)&n_edges
        };
        if (hipLaunchCooperativeKernel((const void*)fused_edge_classifier,
                                       dim3(grid), dim3(256), args, 0,
                                       stream) == hipSuccess)
            return;
    }

    // --- fallback: proven three-kernel pipeline ---
    unsigned short* Bhi = (unsigned short*)((char*)d_ws + p_bytes);
    unsigned short* Blo = Bhi + b_elems;
    pack_W_frags<<<(int)((b_elems + 255) / 256), 256, 0, stream>>>(W1, Bhi, Blo);
    const int nb_nodes = (n_nodes + 63) / 64;
    precompute_P_mfma<<<nb_nodes, 256, 0, stream>>>(emb, Bhi, Blo, P, n_nodes);
    const int nb_edges4 = (n_edges + 63) / 64;
    edge_classify_bf16<<<nb_edges4, 256, 0, stream>>>(src, dst, P, b1, W2, b2, out, n_edges);
}

// Round 10
// 41.086 us; speedup vs baseline: 3.5298x; 3.5298x over previous
//
#include <hip/hip_runtime.h>

#define IN_FEATS 128
#define HIDDEN 32

typedef short v8s __attribute__((ext_vector_type(8)));
typedef unsigned short u16x8 __attribute__((ext_vector_type(8)));
typedef float v4f __attribute__((ext_vector_type(4)));

__device__ __forceinline__ unsigned short f2bf(float x) {
    union { float f; unsigned int u; } v; v.f = x;
    const unsigned int r = v.u + 0x7fffu + ((v.u >> 16) & 1u);   // RNE
    return (unsigned short)(r >> 16);
}
__device__ __forceinline__ float bf2f(unsigned short b) {
    union { float f; unsigned int u; } v; v.u = ((unsigned int)b) << 16;
    return v.f;
}

// ---------------------------------------------------------------------------
// Kernel 1: P[n][0:64] = embed[n] @ [W1s|W1d].T via split-bf16 MFMA.
// Per-block LDS W-pack (replaces the separate pack kernel; W1 reads L2-hit).
// Fragment slot g = (nb*4+ks)*64+lane holds B[k][u], u = nb*16+(lane&15),
// k = ks*32 + ((lane>>4)&3)*8 + j. A uses the identical (group,j)->k map, so
// any common k-permutation cancels in the MFMA K-sum.
// C/D (HW-verified): col = lane&15, row = (lane>>4)*4 + reg.
// Block = 4 waves x 2 sub-tiles x 16 nodes = 128 nodes.
// R9 lesson: keep full TLP, no grid-stride, no grid.sync.
// ---------------------------------------------------------------------------
__global__ __launch_bounds__(256, 4) void precompute_P_mfma(
    const float* __restrict__ embed,
    const float* __restrict__ W1,
    unsigned short* __restrict__ P,        // bf16 [n][64]
    int n_nodes)
{
    __shared__ unsigned short sBhi[8192];  // 16 KB
    __shared__ unsigned short sBlo[8192];  // 16 KB

    const int t    = threadIdx.x;
    const int lane = t & 63;
    const int wave = t >> 6;

    // ---- Phase 0: pack W fragments into LDS (once per block) ----
#pragma unroll
    for (int g0 = 0; g0 < 1024; g0 += 256) {
        const int g   = g0 + t;
        const int gl  = g & 63;
        const int ks  = (g >> 6) & 3;
        const int nb  = g >> 8;
        const int u   = nb * 16 + (gl & 15);
        const int k0  = ks * 32 + ((gl >> 4) & 3) * 8;
        const float* wp = W1 + (u & 31) * (2 * IN_FEATS) + (u >> 5) * IN_FEATS + k0;
        const float4 x0 = *reinterpret_cast<const float4*>(wp);
        const float4 x1 = *reinterpret_cast<const float4*>(wp + 4);
        const float xs[8] = {x0.x, x0.y, x0.z, x0.w, x1.x, x1.y, x1.z, x1.w};
        v8s h, l;
#pragma unroll
        for (int j = 0; j < 8; ++j) {
            const unsigned short hb = f2bf(xs[j]);
            h[j] = (short)hb;
            l[j] = (short)f2bf(xs[j] - bf2f(hb));
        }
        *reinterpret_cast<v8s*>(sBhi + g * 8) = h;
        *reinterpret_cast<v8s*>(sBlo + g * 8) = l;
    }
    __syncthreads();

    // ---- Phase 1: 2 sub-tiles of 16 nodes per wave ----
    const int last = n_nodes - 1;
    const int grp  = lane >> 4;

#pragma unroll
    for (int sub = 0; sub < 2; ++sub) {
        const int node0 = blockIdx.x * 128 + wave * 32 + sub * 16;
        if (node0 >= n_nodes) break;
        const int row = min(node0 + (lane & 15), last);

        v8s ahi[4], alo[4];
#pragma unroll
        for (int ks = 0; ks < 4; ++ks) {
            const float* ap = embed + (size_t)row * IN_FEATS + ks * 32 + grp * 8;
            const float4 x0 = *reinterpret_cast<const float4*>(ap);
            const float4 x1 = *reinterpret_cast<const float4*>(ap + 4);
            const float xs[8] = {x0.x, x0.y, x0.z, x0.w, x1.x, x1.y, x1.z, x1.w};
            v8s h, l;
#pragma unroll
            for (int j = 0; j < 8; ++j) {
                const unsigned short hb = f2bf(xs[j]);
                h[j] = (short)hb;
                l[j] = (short)f2bf(xs[j] - bf2f(hb));
            }
            ahi[ks] = h;
            alo[ks] = l;
        }

#pragma unroll
        for (int nb = 0; nb < 4; ++nb) {
            v8s bhi[4], blo[4];
#pragma unroll
            for (int ks = 0; ks < 4; ++ks) {
                const int fi = ((nb * 4 + ks) * 64 + lane) * 8;
                bhi[ks] = *reinterpret_cast<const v8s*>(sBhi + fi);
                blo[ks] = *reinterpret_cast<const v8s*>(sBlo + fi);
            }
            v4f acc = {0.f, 0.f, 0.f, 0.f};
#pragma unroll
            for (int ks = 0; ks < 4; ++ks) {
                acc = __builtin_amdgcn_mfma_f32_16x16x32_bf16(ahi[ks], bhi[ks], acc, 0, 0, 0);
                acc = __builtin_amdgcn_mfma_f32_16x16x32_bf16(ahi[ks], blo[ks], acc, 0, 0, 0);
                acc = __builtin_amdgcn_mfma_f32_16x16x32_bf16(alo[ks], bhi[ks], acc, 0, 0, 0);
            }
            const int u = nb * 16 + (lane & 15);
#pragma unroll
            for (int r = 0; r < 4; ++r) {
                const int n = node0 + grp * 4 + r;
                if (n < n_nodes)
                    P[(size_t)n * 64 + u] = f2bf(acc[r]);
            }
        }
    }
}

// ---------------------------------------------------------------------------
// Kernel 2: per-edge  logits = relu(Ps[s] + Pd[d] + b1) @ W2.T + b2
// 4 lanes per edge, 2 edges per quad (e and e+64): 4 independent 16B gathers
// in flight per lane. One-shot grid (full TLP -- the R9 lesson).
// ---------------------------------------------------------------------------
__global__ __launch_bounds__(256) void edge_classify_bf16(
    const int* __restrict__ src,
    const int* __restrict__ dst,
    const unsigned short* __restrict__ P,   // bf16 [n][64]
    const float* __restrict__ b1,
    const float* __restrict__ W2,
    const float* __restrict__ b2,
    float* __restrict__ out,
    int n_edges)
{
    const int t  = threadIdx.x;
    const int q  = t & 3;                       // quad lane: units 8q..8q+7
    const int e0 = blockIdx.x * 128 + (t >> 2);
    const int e1 = e0 + 64;
    if (e0 >= n_edges) return;
    const bool has1 = (e1 < n_edges);

    const int s0 = src[e0], d0 = dst[e0];
    const int s1 = has1 ? src[e1] : s0;
    const int d1 = has1 ? dst[e1] : d0;

    const u16x8 ps0 = *reinterpret_cast<const u16x8*>(P + (size_t)s0 * 64 + q * 8);
    const u16x8 pd0 = *reinterpret_cast<const u16x8*>(P + (size_t)d0 * 64 + 32 + q * 8);
    const u16x8 ps1 = *reinterpret_cast<const u16x8*>(P + (size_t)s1 * 64 + q * 8);
    const u16x8 pd1 = *reinterpret_cast<const u16x8*>(P + (size_t)d1 * 64 + 32 + q * 8);

    const float4 b1a = *reinterpret_cast<const float4*>(b1 + q * 8);
    const float4 b1b = *reinterpret_cast<const float4*>(b1 + q * 8 + 4);
    const float4 w0a = *reinterpret_cast<const float4*>(W2 + q * 8);
    const float4 w0b = *reinterpret_cast<const float4*>(W2 + q * 8 + 4);
    const float4 w1a = *reinterpret_cast<const float4*>(W2 + HIDDEN + q * 8);
    const float4 w1b = *reinterpret_cast<const float4*>(W2 + HIDDEN + q * 8 + 4);
    const float bb1[8] = {b1a.x, b1a.y, b1a.z, b1a.w, b1b.x, b1b.y, b1b.z, b1b.w};
    const float ww0[8] = {w0a.x, w0a.y, w0a.z, w0a.w, w0b.x, w0b.y, w0b.z, w0b.w};
    const float ww1[8] = {w1a.x, w1a.y, w1a.z, w1a.w, w1b.x, w1b.y, w1b.z, w1b.w};

    float a0 = 0.f, a1 = 0.f, c0 = 0.f, c1 = 0.f;
#pragma unroll
    for (int j = 0; j < 8; ++j) {
        float h0 = bf2f(ps0[j]) + bf2f(pd0[j]) + bb1[j];
        float h1 = bf2f(ps1[j]) + bf2f(pd1[j]) + bb1[j];
        h0 = fmaxf(h0, 0.f);
        h1 = fmaxf(h1, 0.f);
        a0 = fmaf(h0, ww0[j], a0);
        a1 = fmaf(h0, ww1[j], a1);
        c0 = fmaf(h1, ww0[j], c0);
        c1 = fmaf(h1, ww1[j], c1);
    }
    a0 += __shfl_xor(a0, 1); a0 += __shfl_xor(a0, 2);
    a1 += __shfl_xor(a1, 1); a1 += __shfl_xor(a1, 2);
    c0 += __shfl_xor(c0, 1); c0 += __shfl_xor(c0, 2);
    c1 += __shfl_xor(c1, 1); c1 += __shfl_xor(c1, 2);
    if (q == 0) {
        *reinterpret_cast<float2*>(out + (size_t)e0 * 2) =
            make_float2(a0 + b2[0], a1 + b2[1]);
        if (has1)
            *reinterpret_cast<float2*>(out + (size_t)e1 * 2) =
                make_float2(c0 + b2[0], c1 + b2[1]);
    }
}

// ---------------------------------------------------------------------------
// Fallback (only if workspace too small): direct per-edge computation.
// ---------------------------------------------------------------------------
__global__ __launch_bounds__(256) void edge_direct(
    const int* __restrict__ src, const int* __restrict__ dst,
    const float* __restrict__ embed,
    const float* __restrict__ W1, const float* __restrict__ b1,
    const float* __restrict__ W2, const float* __restrict__ b2,
    float* __restrict__ out, int n_edges)
{
    const int e = blockIdx.x * 256 + threadIdx.x;
    if (e >= n_edges) return;
    const int s = src[e], d = dst[e];
    const float* se = embed + (size_t)s * IN_FEATS;
    const float* de = embed + (size_t)d * IN_FEATS;

    float acc[HIDDEN];
#pragma unroll
    for (int hh = 0; hh < HIDDEN; ++hh) acc[hh] = b1[hh];

    for (int c = 0; c < 4; ++c) {
        float es[32], ed[32];
#pragma unroll
        for (int q = 0; q < 8; ++q) {
            const float4 v = *reinterpret_cast<const float4*>(se + c * 32 + q * 4);
            es[q*4+0] = v.x; es[q*4+1] = v.y; es[q*4+2] = v.z; es[q*4+3] = v.w;
            const float4 u = *reinterpret_cast<const float4*>(de + c * 32 + q * 4);
            ed[q*4+0] = u.x; ed[q*4+1] = u.y; ed[q*4+2] = u.z; ed[q*4+3] = u.w;
        }
#pragma unroll
        for (int hh = 0; hh < HIDDEN; ++hh) {
            float acch = acc[hh];
#pragma unroll
            for (int k = 0; k < 32; ++k) {
                acch = fmaf(es[k], W1[hh * 256 + c * 32 + k], acch);
                acch = fmaf(ed[k], W1[hh * 256 + 128 + c * 32 + k], acch);
            }
            acc[hh] = acch;
        }
    }

    float l0 = b2[0], l1 = b2[1];
#pragma unroll
    for (int hh = 0; hh < HIDDEN; ++hh) {
        const float hv = fmaxf(acc[hh], 0.f);
        l0 = fmaf(hv, W2[hh], l0);
        l1 = fmaf(hv, W2[HIDDEN + hh], l1);
    }
    *reinterpret_cast<float2*>(out + (size_t)e * 2) = make_float2(l0, l1);
}

extern "C" void kernel_launch(void* const* d_in, const int* in_sizes, int n_in,
                              void* d_out, int out_size, void* d_ws, size_t ws_size,
                              hipStream_t stream)
{
    const int*   src = (const int*)d_in[0];
    const int*   dst = (const int*)d_in[1];
    const float* emb = (const float*)d_in[2];
    const float* W1  = (const float*)d_in[3];
    const float* b1  = (const float*)d_in[4];
    const float* W2  = (const float*)d_in[5];
    const float* b2  = (const float*)d_in[6];
    float* out = (float*)d_out;

    const int n_edges = in_sizes[0];
    const int n_nodes = in_sizes[2] / IN_FEATS;

    const size_t p_bytes = (size_t)n_nodes * 64 * sizeof(unsigned short);

    if (ws_size >= p_bytes) {
        unsigned short* P = (unsigned short*)d_ws;
        const int nb_nodes = (n_nodes + 127) / 128;   // 128 nodes per block
        precompute_P_mfma<<<nb_nodes, 256, 0, stream>>>(emb, W1, P, n_nodes);
        const int nb_edges = (n_edges + 127) / 128;   // 128 edges per block
        edge_classify_bf16<<<nb_edges, 256, 0, stream>>>(src, dst, P, b1, W2, b2, out, n_edges);
    } else {
        const int nb_edges = (n_edges + 255) / 256;
        edge_direct<<<nb_edges, 256, 0, stream>>>(src, dst, emb, W1, b1, W2, b2, out, n_edges);
    }
}